// Round 1
// baseline (975.477 us; speedup 1.0000x reference)
//
#include <hip/hip_runtime.h>

// FSMRELoss: B=8, N=128, L=32
//   input  [B,N,N,L,L] f32, target [B,N,N,L] i32 in {0,1}
//   loss      = sum_{i!=j,k} ce(p,g) / (N*(N-1)*L) / B,  p = input[b,i,j,k,k]
//   single    = mean correct over i!=j pairs*labels, correct = g ? (p==rowmax) : !(p==rowmax)
//   multi     = mean over i!=j pairs of AND_k correct
// Memory-bound: 512 MiB input sweep. One wave per pair (4 KiB contiguous).

#define BB 8
#define NN 128
#define LL 32

__global__ void fsmre_init_ws(float* ws) {
    if (threadIdx.x < 3) ws[threadIdx.x] = 0.0f;
}

__global__ __launch_bounds__(256) void fsmre_main(const float* __restrict__ input,
                                                  const int* __restrict__ target,
                                                  float* __restrict__ ws) {
    const int lane = threadIdx.x & 63;
    const int grp  = lane >> 3;        // row-group 0..7
    const int sub  = lane & 7;         // sub-position within row (4 floats each)
    const int comp = grp & 3;          // which float4 component holds the diag candidate

    const int wavesPerBlock = blockDim.x >> 6;
    const int waveId = blockIdx.x * wavesPerBlock + (threadIdx.x >> 6);
    const int wavesTotal = gridDim.x * wavesPerBlock;
    const int nPairs = BB * NN * NN;   // 131072

    float acc_ce = 0.0f, acc_single = 0.0f, acc_multi = 0.0f;

    for (int P = waveId; P < nPairs; P += wavesTotal) {
        const int ij = P & (NN * NN - 1);
        const int i = ij >> 7, j = ij & (NN - 1);
        if (i == j) continue;          // wave-uniform: skip diagonal pairs entirely

        const float4* __restrict__ base = (const float4*)(input + (long long)P * (LL * LL));
        const int*    __restrict__ tb   = target + (long long)P * LL;

        bool all_ok = true;
        float ce_l = 0.0f;
        int single_l = 0;

        #pragma unroll
        for (int v = 0; v < 4; ++v) {
            float4 q = base[v * 64 + lane];          // fully coalesced 1 KiB per instr
            const int r = v * 8 + grp;               // row (= label k) this group owns

            // row max across 8 sub-lanes
            float m = fmaxf(fmaxf(q.x, q.y), fmaxf(q.z, q.w));
            m = fmaxf(m, __shfl_xor(m, 1, 64));
            m = fmaxf(m, __shfl_xor(m, 2, 64));
            m = fmaxf(m, __shfl_xor(m, 4, 64));

            // diagonal element p = row r, column r: held by sub-lane (r>>2), component (r&3)==(grp&3)
            float cand = (comp == 0) ? q.x : (comp == 1) ? q.y : (comp == 2) ? q.z : q.w;
            const int src = (lane & 56) | (2 * v + (grp >> 2));
            float p = __shfl(cand, src, 64);

            const int t = tb[r];                      // broadcast across 8 lanes
            const bool is_max = (p == m);
            const bool ok = t ? is_max : !is_max;
            all_ok &= ok;

            if (sub == 0) {                           // one lane per row accumulates
                ce_l += t ? -logf(p) : -logf(1.0f - p);
                single_l += ok ? 1 : 0;
            }
        }

        acc_ce += ce_l;
        acc_single += (float)single_l;
        if (__all(all_ok)) {                          // AND over all 32 rows of this pair
            if (lane == 0) acc_multi += 1.0f;
        }
    }

    // wave reduction
    #pragma unroll
    for (int d = 1; d < 64; d <<= 1) {
        acc_ce     += __shfl_xor(acc_ce, d, 64);
        acc_single += __shfl_xor(acc_single, d, 64);
        acc_multi  += __shfl_xor(acc_multi, d, 64);
    }
    if (lane == 0) {
        atomicAdd(&ws[0], acc_ce);
        atomicAdd(&ws[1], acc_single);
        atomicAdd(&ws[2], acc_multi);
    }
}

__global__ void fsmre_finalize(const float* __restrict__ ws, float* __restrict__ out) {
    if (threadIdx.x == 0) {
        const double pairs = (double)BB * NN * (NN - 1);          // 130048
        out[0] = (float)((double)ws[0] / ((double)NN * (NN - 1) * LL) / (double)BB);
        out[1] = (float)((double)ws[1] / (pairs * LL));
        out[2] = (float)((double)ws[2] / pairs);
    }
}

extern "C" void kernel_launch(void* const* d_in, const int* in_sizes, int n_in,
                              void* d_out, int out_size, void* d_ws, size_t ws_size,
                              hipStream_t stream) {
    const float* input  = (const float*)d_in[0];
    const int*   target = (const int*)d_in[1];
    float* out = (float*)d_out;
    float* ws  = (float*)d_ws;

    fsmre_init_ws<<<1, 64, 0, stream>>>(ws);

    const int blocks = 2048;   // 8192 waves -> 16 pairs/wave, saturates 256 CUs
    fsmre_main<<<blocks, 256, 0, stream>>>(input, target, ws);

    fsmre_finalize<<<1, 64, 0, stream>>>(ws, out);
}

// Round 2
// 921.304 us; speedup vs baseline: 1.0588x; 1.0588x over previous
//
#include <hip/hip_runtime.h>

// FSMRELoss: B=8, N=128, L=32
//   input  [B,N,N,L,L] f32, target [B,N,N,L] i32 in {0,1}
//   loss   = sum_{i!=j,k} -log(g?p:1-p) / (N*(N-1)*L*B),  p = input[b,i,j,k,k]
//   single = mean over (i!=j, k) of (g ? p==rowmax : p!=rowmax)
//   multi  = mean over (i!=j) of AND_k correct
//
// R1 post-mortem: VGPR=16 => compiler serialized loads; latency-bound at 7.6% HBM.
// R2: PF=2 pairs batched, all loads issued first (8 KB in flight / wave);
//     diag comparison done on holder lane (no bpermute); branchless __logf.

#define BB 8
#define NN 128
#define LL 32
#define NPAIRS (BB * NN * NN)      // 131072
#define NWAVES 8192                // 2048 blocks * 4 waves
#define PPW (NPAIRS / NWAVES)      // 16 pairs per wave
#define PF 2                       // pairs per chunk
#define NCHUNK (PPW / PF)          // 8 chunks

__global__ void fsmre_init_ws(float* ws) {
    if (threadIdx.x < 3) ws[threadIdx.x] = 0.0f;
}

__global__ __launch_bounds__(256, 4) void fsmre_main(const float* __restrict__ input,
                                                     const int* __restrict__ target,
                                                     float* __restrict__ ws) {
    const int lane = threadIdx.x & 63;
    const int grp  = lane >> 3;        // row-group 0..7 (owns row v*8+grp at step v)
    const int sub  = lane & 7;         // position within row (4 floats each)
    const int comp = grp & 3;          // float4 component of the diag candidate

    const int waveId = blockIdx.x * (blockDim.x >> 6) + (threadIdx.x >> 6);
    const int P0 = waveId * PPW;       // contiguous 16-pair chunk per wave (64 KB)

    float acc_ce = 0.0f, acc_single = 0.0f, acc_multi = 0.0f;

    for (int c = 0; c < NCHUNK; ++c) {
        const int Pa = P0 + c * PF;

        // ---- issue ALL loads for PF pairs first (memory ILP) ----
        float4 q[PF][4];
        int    tq[PF][4];
        #pragma unroll
        for (int p = 0; p < PF; ++p) {
            const float4* __restrict__ bp = (const float4*)input + (long long)(Pa + p) * (LL * LL / 4);
            #pragma unroll
            for (int v = 0; v < 4; ++v) q[p][v] = bp[v * 64 + lane];   // 1 KiB coalesced each
            const int* __restrict__ tb = target + (long long)(Pa + p) * LL;
            #pragma unroll
            for (int v = 0; v < 4; ++v) tq[p][v] = tb[v * 8 + grp];    // broadcast within group
        }

        // ---- compute ----
        #pragma unroll
        for (int p = 0; p < PF; ++p) {
            const int P  = Pa + p;
            const int ij = P & (NN * NN - 1);
            const bool offd = ((ij >> 7) != (ij & (NN - 1)));          // i != j (wave-uniform)

            bool all_ok = true;
            float ce = 0.0f;
            int single = 0;

            #pragma unroll
            for (int v = 0; v < 4; ++v) {
                const float4 qq = q[p][v];
                // row max over the 8 sub-lanes of this group
                float m = fmaxf(fmaxf(qq.x, qq.y), fmaxf(qq.z, qq.w));
                m = fmaxf(m, __shfl_xor(m, 1, 64));
                m = fmaxf(m, __shfl_xor(m, 2, 64));
                m = fmaxf(m, __shfl_xor(m, 4, 64));

                // diag element of row r=v*8+grp lives on sub-lane 2v+(grp>>2), component grp&3
                const float pd = (comp == 0) ? qq.x : (comp == 1) ? qq.y : (comp == 2) ? qq.z : qq.w;
                const bool holder = (sub == 2 * v + (grp >> 2));
                const int  t = tq[p][v];
                const bool is_max = (pd == m);
                const bool okr = t ? is_max : !is_max;

                // branchless: non-holders log(1)=0
                const float val = holder ? (t ? pd : 1.0f - pd) : 1.0f;
                ce -= __logf(val);
                single += (holder && okr) ? 1 : 0;
                all_ok &= (!holder) || okr;
            }

            if (offd) {                                   // wave-uniform mask
                acc_ce += ce;
                acc_single += (float)single;
                if (__all(all_ok) && lane == 0) acc_multi += 1.0f;
            }
        }
    }

    // wave reduction
    #pragma unroll
    for (int d = 1; d < 64; d <<= 1) {
        acc_ce     += __shfl_xor(acc_ce, d, 64);
        acc_single += __shfl_xor(acc_single, d, 64);
        acc_multi  += __shfl_xor(acc_multi, d, 64);
    }
    if (lane == 0) {
        atomicAdd(&ws[0], acc_ce);
        atomicAdd(&ws[1], acc_single);
        atomicAdd(&ws[2], acc_multi);
    }
}

__global__ void fsmre_finalize(const float* __restrict__ ws, float* __restrict__ out) {
    if (threadIdx.x == 0) {
        const double pairs = (double)BB * NN * (NN - 1);          // 130048
        out[0] = (float)((double)ws[0] / ((double)NN * (NN - 1) * LL) / (double)BB);
        out[1] = (float)((double)ws[1] / (pairs * LL));
        out[2] = (float)((double)ws[2] / pairs);
    }
}

extern "C" void kernel_launch(void* const* d_in, const int* in_sizes, int n_in,
                              void* d_out, int out_size, void* d_ws, size_t ws_size,
                              hipStream_t stream) {
    const float* input  = (const float*)d_in[0];
    const int*   target = (const int*)d_in[1];
    float* out = (float*)d_out;
    float* ws  = (float*)d_ws;

    fsmre_init_ws<<<1, 64, 0, stream>>>(ws);
    fsmre_main<<<NWAVES / 4, 256, 0, stream>>>(input, target, ws);   // 2048 blocks
    fsmre_finalize<<<1, 64, 0, stream>>>(ws, out);
}

// Round 3
// 757.086 us; speedup vs baseline: 1.2885x; 1.2169x over previous
//
#include <hip/hip_runtime.h>
#include <stdint.h>

// FSMRELoss: B=8, N=128, L=32
//   input  [B,N,N,L,L] f32, target [B,N,N,L] i32 in {0,1}
//   loss   = sum_{i!=j,k} -log(g?p:1-p) / (N*(N-1)*L*B),  p = input[b,i,j,k,k]
//   single = mean over (i!=j, k) of (g ? p==rowmax : p!=rowmax)
//   multi  = mean over (i!=j) of AND_k correct
//
// R2 post-mortem: compiler serialized register loads (VGPR=32), MLP~1-2,
// latency-bound at 1.4 TB/s delivered. R3: async global_load_lds staging
// (no VGPR targets => burst of 16 loads stays in flight), double-buffered
// per-wave private LDS, consumption identical to verified R2 math.

#define BB 8
#define NN 128
#define LL 32
#define NPAIRS (BB * NN * NN)        // 131072
#define NBLOCKS 512
#define WPB 4                        // waves per block
#define NWAVES (NBLOCKS * WPB)       // 2048 (all co-resident: 2 blocks/CU)
#define PPW (NPAIRS / NWAVES)        // 64 pairs per wave
#define PF 2                         // pairs per chunk (8 KB)
#define NCHUNK (PPW / PF)            // 32
#define PAIR_FLOATS (LL * LL)        // 1024
#define CHUNK_FLOATS (PF * PAIR_FLOATS)  // 2048 floats = 8 KB

__global__ void fsmre_init_ws(float* ws) {
    if (threadIdx.x < 3) ws[threadIdx.x] = 0.0f;
}

// CK-style cast helpers for global_load_lds
__device__ __forceinline__ void gll16(const float* g, float* l) {
#if __has_builtin(__builtin_amdgcn_global_load_lds)
    auto* lds3 = reinterpret_cast<__attribute__((address_space(3))) uint32_t*>(
        (uint32_t)(uintptr_t)l);
    __builtin_amdgcn_global_load_lds(
        (const __attribute__((address_space(1))) uint32_t*)(const void*)g,
        lds3, 16, 0, 0);
#else
    // fallback: synchronous staging (slow, but compiles anywhere)
    *(float4*)l = *(const float4*)g;
#endif
}

__global__ __launch_bounds__(256, 2) void fsmre_main(const float* __restrict__ input,
                                                     const int* __restrict__ target,
                                                     float* __restrict__ ws) {
    __shared__ float smem[WPB * 2 * CHUNK_FLOATS];   // 4 waves * 2 bufs * 8 KB = 64 KB

    const int lane = threadIdx.x & 63;
    const int wib  = threadIdx.x >> 6;
    const int grp  = lane >> 3;        // row-group 0..7
    const int sub  = lane & 7;         // position within row
    const int comp = grp & 3;          // float4 component of diag candidate

    const int waveId = blockIdx.x * WPB + wib;
    const int P0 = waveId * PPW;       // contiguous 64-pair region (256 KB)

    float* myLds = smem + wib * (2 * CHUNK_FLOATS);

    float acc_ce = 0.0f, acc_single = 0.0f, acc_multi = 0.0f;

    // stage chunk 0 into buffer 0
    {
        const float* g0 = input + (long long)P0 * PAIR_FLOATS + lane * 4;
        float* l0 = myLds + lane * 4;
        #pragma unroll
        for (int s = 0; s < PF * 4; ++s) gll16(g0 + s * 256, l0 + s * 256);
    }

    for (int c = 0; c < NCHUNK; ++c) {
        const int buf = c & 1;

        // prefetch next chunk into the other buffer (stays in flight during drain)
        if (c + 1 < NCHUNK) {
            const float* g0 = input + (long long)(P0 + (c + 1) * PF) * PAIR_FLOATS + lane * 4;
            float* l0 = myLds + (buf ^ 1) * CHUNK_FLOATS + lane * 4;
            #pragma unroll
            for (int s = 0; s < PF * 4; ++s) gll16(g0 + s * 256, l0 + s * 256);
        }

        // targets for this chunk (register loads; drained by the same waitcnt)
        int tq[PF][4];
        #pragma unroll
        for (int p = 0; p < PF; ++p) {
            const int* __restrict__ tb = target + (long long)(P0 + c * PF + p) * LL;
            #pragma unroll
            for (int v = 0; v < 4; ++v) tq[p][v] = tb[v * 8 + grp];
        }

        asm volatile("s_waitcnt vmcnt(0)" ::: "memory");

        // ---- consume (identical math to verified R2) ----
        #pragma unroll
        for (int p = 0; p < PF; ++p) {
            const int P  = P0 + c * PF + p;
            const int ij = P & (NN * NN - 1);
            const bool offd = ((ij >> 7) != (ij & (NN - 1)));   // i != j (wave-uniform)

            const float* lp = myLds + buf * CHUNK_FLOATS + p * PAIR_FLOATS;

            bool all_ok = true;
            float ce = 0.0f;
            int single = 0;

            #pragma unroll
            for (int v = 0; v < 4; ++v) {
                const float4 qq = *((const float4*)(lp + v * 256) + lane);  // ds_read_b128, conflict-free

                float m = fmaxf(fmaxf(qq.x, qq.y), fmaxf(qq.z, qq.w));
                m = fmaxf(m, __shfl_xor(m, 1, 64));
                m = fmaxf(m, __shfl_xor(m, 2, 64));
                m = fmaxf(m, __shfl_xor(m, 4, 64));

                const float pd = (comp == 0) ? qq.x : (comp == 1) ? qq.y : (comp == 2) ? qq.z : qq.w;
                const bool holder = (sub == 2 * v + (grp >> 2));
                const int  t = tq[p][v];
                const bool is_max = (pd == m);
                const bool okr = t ? is_max : !is_max;

                const float val = holder ? (t ? pd : 1.0f - pd) : 1.0f;
                ce -= __logf(val);
                single += (holder && okr) ? 1 : 0;
                all_ok &= (!holder) || okr;
            }

            if (offd) {
                acc_ce += ce;
                acc_single += (float)single;
                if (__all(all_ok) && lane == 0) acc_multi += 1.0f;
            }
        }
    }

    // wave reduction
    #pragma unroll
    for (int d = 1; d < 64; d <<= 1) {
        acc_ce     += __shfl_xor(acc_ce, d, 64);
        acc_single += __shfl_xor(acc_single, d, 64);
        acc_multi  += __shfl_xor(acc_multi, d, 64);
    }
    if (lane == 0) {
        atomicAdd(&ws[0], acc_ce);
        atomicAdd(&ws[1], acc_single);
        atomicAdd(&ws[2], acc_multi);
    }
}

__global__ void fsmre_finalize(const float* __restrict__ ws, float* __restrict__ out) {
    if (threadIdx.x == 0) {
        const double pairs = (double)BB * NN * (NN - 1);          // 130048
        out[0] = (float)((double)ws[0] / ((double)NN * (NN - 1) * LL) / (double)BB);
        out[1] = (float)((double)ws[1] / (pairs * LL));
        out[2] = (float)((double)ws[2] / pairs);
    }
}

extern "C" void kernel_launch(void* const* d_in, const int* in_sizes, int n_in,
                              void* d_out, int out_size, void* d_ws, size_t ws_size,
                              hipStream_t stream) {
    const float* input  = (const float*)d_in[0];
    const int*   target = (const int*)d_in[1];
    float* out = (float*)d_out;
    float* ws  = (float*)d_ws;

    fsmre_init_ws<<<1, 64, 0, stream>>>(ws);
    fsmre_main<<<NBLOCKS, 256, 0, stream>>>(input, target, ws);
    fsmre_finalize<<<1, 64, 0, stream>>>(ws, out);
}